// Round 9
// baseline (4256.070 us; speedup 1.0000x reference)
//
#include <hip/hip_runtime.h>
#include <hip/hip_bf16.h>
#include <cstdint>
#include <cstddef>

// BiLSTM-CRF forward + Viterbi decode, T=4096, E=300, H2=256, K=32.
//   K1 zx_gemm    : zx[t] = Wih @ embed[token] + b (both dirs, batched)
//   K2 lstm_kernel: one CU per direction. R9: 512 thr @ launch_bounds(512,2)
//                   -> 256-reg/wave budget. Thread (p,l) owns the 8 rotated
//                   gate-rows of elem-pair {2p,2p+1}, k-slice l: wq[128] int8
//                   dwords + hd[16] + ~30 live = ~175 regs, fits ARCH with
//                   headroom. (R7/R8 at 1024thr/128-budget: allocator parked
//                   wq in AGPRs -> 1 v_accvgpr_read per dot = +512 cy/SIMD/
//                   step; asm "v" constraints could not change residency,
//                   VGPR_Count stayed 64.) Same rotate-reduce DPP scheme per
//                   elem group; gates distributed (lane l = gate l, both
//                   elems); c/h update in lane 0; custom lgkm-only barrier.
//   K3 feat_kernel: feats = [hf|hb] @ W_out^T + b_out (unpack int8 h)
//   K4a/b/c       : Viterbi via max-plus chunk composition
//   K5 compose, K6 backtrace: parallel backtrace reconstruction.

#define T_LEN 4096
#define E_DIM 300
#define H2 256
#define G4 1024
#define KTAGS 32
#define START_TAG 30
#define STOP_TAG 31
#define NEGV (-10000.0f)
#define NCHUNK 128
#define CLEN 32

// inline-asm dot4 (int8x4 dot product accumulate)
__device__ __forceinline__ int dot4a(int a, int b, int c) {
  int d;
  asm("v_dot4_i32_i8 %0, %1, %2, %3" : "=v"(d) : "v"(a), "v"(b), "v"(c));
  return d;
}

__device__ __forceinline__ float fast_sigmoid(float x) {
  return __builtin_amdgcn_rcpf(1.0f + __expf(-x));
}
__device__ __forceinline__ float fast_tanh(float x) {
  return 1.0f - 2.0f * __builtin_amdgcn_rcpf(__expf(2.0f * x) + 1.0f);
}

template <int CTRL>
__device__ __forceinline__ float dppmovf(float x) {
  return __int_as_float(
      __builtin_amdgcn_update_dpp(0, __float_as_int(x), CTRL, 0xF, 0xF, true));
}
template <int CTRL>
__device__ __forceinline__ int dppmovi(int x) {
  return __builtin_amdgcn_update_dpp(0, x, CTRL, 0xF, 0xF, true);
}

// ---------------- K1: input projection GEMM ----------------
__global__ __launch_bounds__(256) void zx_gemm(
    const int* __restrict__ sent, const float* __restrict__ embed,
    const float* __restrict__ Wih_f, const float* __restrict__ b_f,
    const float* __restrict__ Wih_b, const float* __restrict__ b_b,
    float* __restrict__ zxF, float* __restrict__ zxB)
{
  const int dir = blockIdx.y;
  const int t0 = blockIdx.x * 8;
  const float* __restrict__ Wih = dir ? Wih_b : Wih_f;
  const float* __restrict__ bias = dir ? b_b : b_f;
  float* __restrict__ zx = dir ? zxB : zxF;

  __shared__ __align__(16) float xs[8 * E_DIM];
  const int tid = threadIdx.x;
  for (int ti = 0; ti < 8; ++ti) {
    int p = t0 + ti;
    int tok = sent[dir ? (T_LEN - 1 - p) : p];
    const float* er = embed + (size_t)tok * E_DIM;
    for (int k = tid; k < E_DIM; k += 256) xs[ti * E_DIM + k] = er[k];
  }
  __syncthreads();

  const int r = tid;
  float acc[4][8];
#pragma unroll
  for (int g = 0; g < 4; ++g) {
    float bv = bias[g * 256 + r];
#pragma unroll
    for (int ti = 0; ti < 8; ++ti) acc[g][ti] = bv;
  }
  const float4* w0p = (const float4*)(Wih + (size_t)(r) * E_DIM);
  const float4* w1p = (const float4*)(Wih + (size_t)(256 + r) * E_DIM);
  const float4* w2p = (const float4*)(Wih + (size_t)(512 + r) * E_DIM);
  const float4* w3p = (const float4*)(Wih + (size_t)(768 + r) * E_DIM);
  for (int k4 = 0; k4 < E_DIM / 4; ++k4) {
    float4 w0 = w0p[k4], w1 = w1p[k4], w2 = w2p[k4], w3 = w3p[k4];
#pragma unroll
    for (int ti = 0; ti < 8; ++ti) {
      float4 x4 = *(const float4*)(xs + ti * E_DIM + k4 * 4);
      acc[0][ti] += w0.x * x4.x + w0.y * x4.y + w0.z * x4.z + w0.w * x4.w;
      acc[1][ti] += w1.x * x4.x + w1.y * x4.y + w1.z * x4.z + w1.w * x4.w;
      acc[2][ti] += w2.x * x4.x + w2.y * x4.y + w2.z * x4.z + w2.w * x4.w;
      acc[3][ti] += w3.x * x4.x + w3.y * x4.y + w3.z * x4.z + w3.w * x4.w;
    }
  }
#pragma unroll
  for (int g = 0; g < 4; ++g)
#pragma unroll
    for (int ti = 0; ti < 8; ++ti)
      zx[(size_t)(t0 + ti) * G4 + g * 256 + r] = acc[g][ti];
}

// ---------------- K2: int8 weight-stationary LSTM (512thr, pair/thread) -----
__global__ __launch_bounds__(512, 2) void lstm_kernel(
    const float* __restrict__ Whh_f, const float* __restrict__ Whh_b,
    const float* __restrict__ h0, const float* __restrict__ c0,
    const float* __restrict__ zxF, const float* __restrict__ zxB,
    uint32_t* __restrict__ hhF, uint32_t* __restrict__ hhB)
{
  const int d = blockIdx.x;
  const float* __restrict__ Whh = d ? Whh_b : Whh_f;
  const float* __restrict__ zxd = d ? zxB : zxF;
  uint32_t* __restrict__ hh = d ? hhB : hhF;

  const int tid = threadIdx.x;
  const int l = tid & 3;   // k-slice AND my gate
  const int p = tid >> 2;  // elem pair 0..127 (elems 2p, 2p+1)

  __shared__ __align__(16) uint32_t hQA[64];  // int8-packed h, 256 B
  __shared__ __align__(16) uint32_t hQB[64];

  // ---- one-time: quantize 8 rotated gate-rows (2 elems x 4 gates) ----
  // group G (elem 2p+G): s -> global row ((l+s)&3)*256 + 2p+G, dwords
  // [l*16, l*16+16). wq[G*64 + s*16 + i].
  int wq[128];
  float swA, swB;
#pragma unroll
  for (int grp = 0; grp < 2; ++grp) {
    int e = 2 * p + grp;
#pragma unroll
    for (int s = 0; s < 4; ++s) {
      int r = (l + s) & 3;
      const float4* Wr = (const float4*)(Whh + (size_t)(r * 256 + e) * H2);
      float amax = 1e-12f;
      for (int i = 0; i < 64; ++i) {  // full-row scan: scale consistent across slices
        float4 v = Wr[i];
        amax = fmaxf(amax, fmaxf(fmaxf(fabsf(v.x), fabsf(v.y)),
                                 fmaxf(fabsf(v.z), fabsf(v.w))));
      }
      const float winv = 127.f / amax;
      if (s == 0) { if (grp == 0) swA = amax / 127.f; else swB = amax / 127.f; }
      for (int i = 0; i < 16; ++i) {
        float4 v = Wr[l * 16 + i];
        int b0 = ((int)rintf(v.x * winv)) & 255;
        int b1 = ((int)rintf(v.y * winv)) & 255;
        int b2 = ((int)rintf(v.z * winv)) & 255;
        int b3 = ((int)rintf(v.w * winv)) & 255;
        wq[grp * 64 + s * 16 + i] = b0 | (b1 << 8) | (b2 << 16) | (b3 << 24);
      }
    }
  }

  // ---- h0 scale (redundant scan) + seed ----
  float h0max = 1e-12f;
  const float4* H0 = (const float4*)(h0 + d * H2);
  for (int i = 0; i < 64; ++i) {
    float4 v = H0[i];
    h0max = fmaxf(h0max, fmaxf(fmaxf(fabsf(v.x), fabsf(v.y)),
                               fmaxf(fabsf(v.z), fabsf(v.w))));
  }
  if (tid < 64) {
    float inv0 = 127.f / h0max;
    float4 v = H0[tid];
    int b0 = ((int)rintf(v.x * inv0)) & 255;
    int b1 = ((int)rintf(v.y * inv0)) & 255;
    int b2 = ((int)rintf(v.z * inv0)) & 255;
    int b3 = ((int)rintf(v.w * inv0)) & 255;
    hQA[tid] = (uint32_t)(b0 | (b1 << 8) | (b2 << 16) | (b3 << 24));
  }

  const float sfA = swA * (h0max / 127.f), srA = swA * (1.f / 127.f);
  const float sfB = swB * (h0max / 127.f), srB = swB * (1.f / 127.f);
  const bool is_g = (l == 2);
  const bool is_i = (l == 0);

  float c0r = c0[d * H2 + 2 * p];      // live only in lane l==0
  float c1r = c0[d * H2 + 2 * p + 1];

  const float* zp = zxd + l * 256 + 2 * p;  // my gate's zx pair stream
  float2 zcur = *(const float2*)zp;
  uint32_t* hp = hh + tid;  // tid<64 stores h history
  __syncthreads();

  auto step = [&](const uint32_t* hin, uint32_t* hout, float sA, float sB) {
    float2 znext = *(const float2*)(zp + G4);  // prefetch t+1 (overread safe)

    // my k-slice of h: 4 b128 broadcast-group reads
    uint32_t hd[16];
#pragma unroll
    for (int cc = 0; cc < 4; ++cc)
      *(uint4*)(hd + 4 * cc) = *((const uint4*)hin + l * 4 + cc);

    // 8 rotated rows x 16 asm sdot4
    int a0 = 0, a1 = 0, a2 = 0, a3 = 0, b0 = 0, b1 = 0, b2 = 0, b3 = 0;
#pragma unroll
    for (int i = 0; i < 16; ++i) {
      int hv = (int)hd[i];
      a0 = dot4a(wq[i], hv, a0);
      a1 = dot4a(wq[16 + i], hv, a1);
      a2 = dot4a(wq[32 + i], hv, a2);
      a3 = dot4a(wq[48 + i], hv, a3);
      b0 = dot4a(wq[64 + i], hv, b0);
      b1 = dot4a(wq[80 + i], hv, b1);
      b2 = dot4a(wq[96 + i], hv, b2);
      b3 = dot4a(wq[112 + i], hv, b3);
    }
    // rotate-reduce per elem group: lane g ends with gate g's full sum
    int totA = a0;
    totA += dppmovi<0x93>(a1);
    totA += dppmovi<0x4E>(a2);
    totA += dppmovi<0x39>(a3);
    int totB = b0;
    totB += dppmovi<0x93>(b1);
    totB += dppmovi<0x4E>(b2);
    totB += dppmovi<0x39>(b3);
    float zA = (float)totA * sA + zcur.x;
    float zB = (float)totB * sB + zcur.y;

    // distributed gate function (lane 2 = tanh via 2*sigmoid(2x)-1)
    float xA = is_g ? (zA + zA) : zA;
    float xB = is_g ? (zB + zB) : zB;
    float gA = fast_sigmoid(xA);
    float gB = fast_sigmoid(xB);
    float yA = is_g ? (gA + gA - 1.f) : gA;
    float yB = is_g ? (gB + gB - 1.f) : gB;

    // gather f,g,o into lane 0
    float pfA = dppmovf<0xB1>(yA), pgA = dppmovf<0x4E>(yA), poA = dppmovf<0x1B>(yA);
    float pfB = dppmovf<0xB1>(yB), pgB = dppmovf<0x4E>(yB), poB = dppmovf<0x1B>(yB);
    if (is_i) {
      c0r = pfA * c0r + yA * pgA;
      c1r = pfB * c1r + yB * pgB;
      float hv0 = poA * fast_tanh(c0r);
      float hv1 = poB * fast_tanh(c1r);
      int q0 = ((int)rintf(hv0 * 127.f)) & 255;
      int q1 = ((int)rintf(hv1 * 127.f)) & 255;
      ((uint16_t*)hout)[p] = (uint16_t)(q0 | (q1 << 8));
    }
    zcur = znext;
    zp += G4;
    // barrier WITHOUT vmcnt drain: LDS ordering only; zx prefetch in flight
    asm volatile("s_waitcnt lgkmcnt(0)\n\ts_barrier" ::: "memory");
    if (tid < 64) *hp = hout[tid];  // int8 h history (wave 0 only)
    hp += 64;
  };

  step(hQA, hQB, sfA, sfB);
  step(hQB, hQA, srA, srB);
  for (int t = 2; t < T_LEN; t += 2) {
    step(hQA, hQB, srA, srB);
    step(hQB, hQA, srA, srB);
  }
}

// ---------------- K3: feats = [hf|hb] @ W_out^T + b_out ----------------
__global__ __launch_bounds__(256) void feat_kernel(
    const uint32_t* __restrict__ hhF, const uint32_t* __restrict__ hhB,
    const float* __restrict__ W_out, const float* __restrict__ b_out,
    float* __restrict__ feats)
{
  const int p0 = blockIdx.x * 8;
  const int tid = threadIdx.x;
  __shared__ float hs[8 * 520];
#define HIDX(pos, k) ((pos) * 520 + (k) + ((k) >> 6))
  const float s = 1.f / 127.f;
  for (int idx = tid; idx < 512; idx += 256) {  // 8 pos x 64 dwords
    int pos = idx >> 6, dw = idx & 63;
    uint32_t vf = hhF[(size_t)(p0 + pos) * 64 + dw];
    uint32_t vb = hhB[(size_t)(T_LEN - 1 - (p0 + pos)) * 64 + dw];
    int k = dw * 4;
    hs[HIDX(pos, k + 0)] = (float)(int8_t)(vf) * s;
    hs[HIDX(pos, k + 1)] = (float)(int8_t)(vf >> 8) * s;
    hs[HIDX(pos, k + 2)] = (float)(int8_t)(vf >> 16) * s;
    hs[HIDX(pos, k + 3)] = (float)(int8_t)(vf >> 24) * s;
    int kb = 256 + k;
    hs[HIDX(pos, kb + 0)] = (float)(int8_t)(vb) * s;
    hs[HIDX(pos, kb + 1)] = (float)(int8_t)(vb >> 8) * s;
    hs[HIDX(pos, kb + 2)] = (float)(int8_t)(vb >> 16) * s;
    hs[HIDX(pos, kb + 3)] = (float)(int8_t)(vb >> 24) * s;
  }
  __syncthreads();

  const int tag = tid >> 3;
  const int kc = tid & 7;
  float4 w4[16];
  const float4* wp = (const float4*)(W_out + tag * 512 + kc * 64);
#pragma unroll
  for (int i = 0; i < 16; ++i) w4[i] = wp[i];
  const float bo = b_out[tag];

#pragma unroll
  for (int pos = 0; pos < 8; ++pos) {
    const float* hpp = hs + pos * 520 + kc * 64 + kc;
    float a = 0.f;
#pragma unroll
    for (int i = 0; i < 16; ++i) {
      float4 w = w4[i];
      a += w.x * hpp[i * 4] + w.y * hpp[i * 4 + 1] + w.z * hpp[i * 4 + 2] + w.w * hpp[i * 4 + 3];
    }
    a += __shfl_xor(a, 1);
    a += __shfl_xor(a, 2);
    a += __shfl_xor(a, 4);
    if (kc == 0) feats[(size_t)(p0 + pos) * KTAGS + tag] = a + bo;
  }
}

// ---------------- K4a: parallel chunk transfer matrices ----------------
__global__ __launch_bounds__(1024) void vit_phaseA(
    const float* __restrict__ feats, const float* __restrict__ trans,
    float* __restrict__ Cmat)
{
  const int c = blockIdx.x;
  const int tid = threadIdx.x;
  const int i = tid >> 5, j = tid & 31;
  const int t0 = c * CLEN;

  float Trow[32];
#pragma unroll
  for (int k = 0; k < 32; ++k) Trow[k] = trans[i * 32 + k];

  __shared__ float Ca[1024], Cb[1024];
  Ca[tid] = Trow[j] + feats[(size_t)t0 * KTAGS + i];
  __syncthreads();

  float* cur = Ca;
  float* nxt = Cb;
  for (int s = 1; s < CLEN; ++s) {
    float fi = feats[(size_t)(t0 + s) * KTAGS + i];
    float m = Trow[0] + cur[j];
#pragma unroll
    for (int k = 1; k < 32; ++k) m = fmaxf(m, Trow[k] + cur[k * 32 + j]);
    nxt[tid] = m + fi;
    __syncthreads();
    float* tmp = cur; cur = nxt; nxt = tmp;
  }
  Cmat[(size_t)c * 1024 + tid] = cur[tid];
}

// ---------------- K4b: sequential chunk-level pass (tiny) ----------------
__global__ __launch_bounds__(64) void vit_phaseB(
    const float* __restrict__ Cmat, const float* __restrict__ trans,
    float* __restrict__ fvs, float* __restrict__ score_out,
    int* __restrict__ best_out)
{
  const int ln = threadIdx.x;
  const int i = ln & 31;
  float fv = (i == START_TAG) ? 0.0f : NEGV;
  if (ln < 32) fvs[i] = fv;

  for (int c = 0; c < NCHUNK; ++c) {
    const float* Crow = Cmat + (size_t)c * 1024 + i * 32;
    float cr[32];
#pragma unroll
    for (int w = 0; w < 8; ++w) *(float4*)(cr + 4 * w) = *(const float4*)(Crow + 4 * w);
    float m = cr[0] + __shfl(fv, 0);
#pragma unroll
    for (int jj = 1; jj < 32; ++jj) m = fmaxf(m, cr[jj] + __shfl(fv, jj));
    fv = m;
    if (ln < 32) fvs[(c + 1) * 32 + i] = fv;
  }

  float v = fv + trans[STOP_TAG * 32 + i];
  int bi = i;
#pragma unroll
  for (int m = 1; m < 32; m <<= 1) {
    float ov = __shfl_xor(v, m);
    int oi = __shfl_xor(bi, m);
    if (ov > v || (ov == v && oi < bi)) { v = ov; bi = oi; }
  }
  if (ln == 0) { score_out[0] = v; best_out[0] = bi; }
}

// ---------------- K4c: parallel per-chunk bptr regeneration ----------------
__global__ __launch_bounds__(64) void vit_phaseC(
    const float* __restrict__ feats, const float* __restrict__ trans,
    const float* __restrict__ fvs, unsigned char* __restrict__ bptr)
{
  const int c = blockIdx.x;
  const int ln = threadIdx.x;
  const int i = ln & 31;
  const int jb = ln >> 5;
  const int t0 = c * CLEN;

  float Tj[16];
#pragma unroll
  for (int s = 0; s < 16; ++s) Tj[s] = trans[i * 32 + jb * 16 + s];

  float fv = fvs[c * 32 + i];
  float pf = feats[(size_t)t0 * KTAGS + i];

  for (int s = 0; s < CLEN; ++s) {
    float cv[16];
    int cj[16];
#pragma unroll
    for (int ss = 0; ss < 16; ++ss) {
      cv[ss] = __shfl(fv, jb * 16 + ss) + Tj[ss];
      cj[ss] = jb * 16 + ss;
    }
#pragma unroll
    for (int st = 1; st < 16; st <<= 1)
#pragma unroll
      for (int ss = 0; ss < 16; ss += 2 * st)
        if (cv[ss + st] > cv[ss]) { cv[ss] = cv[ss + st]; cj[ss] = cj[ss + st]; }
    float v = cv[0];
    int bj = cj[0];
    float ov = __shfl_xor(v, 32);
    int oj = __shfl_xor(bj, 32);
    if (ov > v || (ov == v && oj < bj)) { v = ov; bj = oj; }

    int t = t0 + s;
    float f = pf;
    int tn = (t + 1 < T_LEN) ? t + 1 : t;
    pf = feats[(size_t)tn * KTAGS + i];
    fv = v + f;
    if (jb == 0) bptr[(size_t)t * KTAGS + i] = (unsigned char)bj;
  }
}

// ---------------- K5: compose 32-step backtrace maps ----------------
__global__ __launch_bounds__(64) void vit_compose(
    const unsigned char* __restrict__ bptr, unsigned char* __restrict__ fmap)
{
  const int m = blockIdx.x;
  __shared__ unsigned char B[32 * 32];
  const int tid = threadIdx.x;
  const uint32_t* src = (const uint32_t*)(bptr + (size_t)m * 1024);
  uint32_t* dstw = (uint32_t*)B;
  for (int idx = tid; idx < 256; idx += 64) dstw[idx] = src[idx];
  __syncthreads();
  if (tid < 32) {
    int y = tid;
#pragma unroll
    for (int tt = 31; tt >= 0; --tt) y = B[tt * 32 + y];
    fmap[m * 32 + tid] = (unsigned char)y;
  }
}

// ---------------- K6: boundary walk + parallel expansion ----------------
__global__ __launch_bounds__(256) void vit_backtrace(
    const unsigned char* __restrict__ bptr, const unsigned char* __restrict__ fmap,
    const int* __restrict__ best, float* __restrict__ path_out)
{
  __shared__ unsigned char F[128 * 32];
  __shared__ unsigned char bound[128];
  const int tid = threadIdx.x;
  const uint32_t* src = (const uint32_t*)fmap;
  uint32_t* dstw = (uint32_t*)F;
  for (int idx = tid; idx < 1024; idx += 256) dstw[idx] = src[idx];
  __syncthreads();
  if (tid == 0) {
    int y = best[0];
    bound[127] = (unsigned char)y;
    for (int m = 127; m >= 1; --m) {
      y = F[m * 32 + y];
      bound[m - 1] = (unsigned char)y;
    }
  }
  __syncthreads();
  if (tid < 128) {
    const int m = tid;
    int y = bound[m];
    path_out[m * 32 + 31] = (float)y;
    for (int tt = 30; tt >= 0; --tt) {
      y = bptr[(size_t)(m * 32 + tt + 1) * 32 + y];
      path_out[m * 32 + tt] = (float)y;
    }
  }
}

extern "C" void kernel_launch(void* const* d_in, const int* in_sizes, int n_in,
                              void* d_out, int out_size, void* d_ws, size_t ws_size,
                              hipStream_t stream)
{
  const int* sent    = (const int*)d_in[0];
  const float* embed = (const float*)d_in[1];
  const float* Wih_f = (const float*)d_in[2];
  const float* Whh_f = (const float*)d_in[3];
  const float* b_f   = (const float*)d_in[4];
  const float* Wih_b = (const float*)d_in[5];
  const float* Whh_b = (const float*)d_in[6];
  const float* b_b   = (const float*)d_in[7];
  const float* W_out = (const float*)d_in[8];
  const float* b_out = (const float*)d_in[9];
  const float* trans = (const float*)d_in[10];
  const float* h0    = (const float*)d_in[11];
  const float* c0    = (const float*)d_in[12];

  float* W = (float*)d_ws;
  float* zxF = W;                                    // 16 MB (dead after lstm)
  float* zxB = zxF + (size_t)T_LEN * G4;             // 16 MB
  float* feats = zxB + (size_t)T_LEN * G4;           // 512 KB
  uint32_t* hhF = (uint32_t*)(feats + (size_t)T_LEN * KTAGS);  // 1 MB (int8 h)
  uint32_t* hhB = hhF + (size_t)T_LEN * 64;          // 1 MB
  int* bestIdx = (int*)(hhB + (size_t)T_LEN * 64);
  unsigned char* bptr = (unsigned char*)(bestIdx + 16);  // 128 KB
  unsigned char* fmap = bptr + (size_t)T_LEN * KTAGS;    // 4 KB
  float* Cmat = zxF;                                 // overlay, 512 KB
  float* fvs = zxF + NCHUNK * 1024;                  // 129*32 floats

  float* out = (float*)d_out;  // out[0]=path_score, out[1..4096]=path tags

  zx_gemm<<<dim3(T_LEN / 8, 2), 256, 0, stream>>>(sent, embed, Wih_f, b_f, Wih_b, b_b, zxF, zxB);
  lstm_kernel<<<2, 512, 0, stream>>>(Whh_f, Whh_b, h0, c0, zxF, zxB, hhF, hhB);
  feat_kernel<<<T_LEN / 8, 256, 0, stream>>>(hhF, hhB, W_out, b_out, feats);
  vit_phaseA<<<NCHUNK, 1024, 0, stream>>>(feats, trans, Cmat);
  vit_phaseB<<<1, 64, 0, stream>>>(Cmat, trans, fvs, out, bestIdx);
  vit_phaseC<<<NCHUNK, 64, 0, stream>>>(feats, trans, fvs, bptr);
  vit_compose<<<128, 64, 0, stream>>>(bptr, fmap);
  vit_backtrace<<<1, 256, 0, stream>>>(bptr, fmap, bestIdx, out + 1);
}

// Round 10
// 3373.807 us; speedup vs baseline: 1.2615x; 1.2615x over previous
//
#include <hip/hip_runtime.h>
#include <hip/hip_bf16.h>
#include <cstdint>
#include <cstddef>

// BiLSTM-CRF forward + Viterbi decode, T=4096, E=300, H2=256, K=32.
//   K1 zx_gemm    : zx[t] = Wih @ embed[token] + b (both dirs, batched)
//   K2 lstm_kernel: one CU per direction, 512 thr @ (512,2). R10: INT4
//                   weights + int4 recurrence-h via v_dot8_i32_i4 — halves
//                   dot wave-instrs (R7/R8/R9 all ~3.57ms across register
//                   configs => dot4 issues at ~4cy => 1024cy/step dot floor;
//                   sdot8 cuts it to 512). h HISTORY stays int8 (separate
//                   LDS staging) so feats/Viterbi see int8 quality; only the
//                   recurrence matvec sees int4. Per-row scales, rotated-row
//                   DPP reduce, distributed gates, lgkm-only barrier (all
//                   carried from R7-R9).
//   K3 feat_kernel: feats = [hf|hb] @ W_out^T + b_out (unpack int8 h)
//   K4a/b/c       : Viterbi via max-plus chunk composition
//   K5 compose, K6 backtrace: parallel backtrace reconstruction.

#define T_LEN 4096
#define E_DIM 300
#define H2 256
#define G4 1024
#define KTAGS 32
#define START_TAG 30
#define STOP_TAG 31
#define NEGV (-10000.0f)
#define NCHUNK 128
#define CLEN 32

#if defined(__has_builtin)
#if __has_builtin(__builtin_amdgcn_sdot8)
#define HAVE_SDOT8 1
#endif
#endif
#ifndef HAVE_SDOT8
#define HAVE_SDOT8 0
#endif

__device__ __forceinline__ int dot8(int a, int b, int c) {
#if HAVE_SDOT8
  return __builtin_amdgcn_sdot8(a, b, c, false);
#else
  int r = c;
#pragma unroll
  for (int i = 0; i < 8; ++i) {
    int an = (a << (28 - 4 * i)) >> 28;
    int bn = (b << (28 - 4 * i)) >> 28;
    r += an * bn;
  }
  return r;
#endif
}

__device__ __forceinline__ float fast_sigmoid(float x) {
  return __builtin_amdgcn_rcpf(1.0f + __expf(-x));
}
__device__ __forceinline__ float fast_tanh(float x) {
  return 1.0f - 2.0f * __builtin_amdgcn_rcpf(__expf(2.0f * x) + 1.0f);
}

template <int CTRL>
__device__ __forceinline__ float dppmovf(float x) {
  return __int_as_float(
      __builtin_amdgcn_update_dpp(0, __float_as_int(x), CTRL, 0xF, 0xF, true));
}
template <int CTRL>
__device__ __forceinline__ int dppmovi(int x) {
  return __builtin_amdgcn_update_dpp(0, x, CTRL, 0xF, 0xF, true);
}

// pack 8 consecutive weights (two float4) into one int4x8 dword
__device__ __forceinline__ int packn(float4 v0, float4 v1, float winv) {
  int n0 = ((int)rintf(v0.x * winv)) & 15;
  int n1 = ((int)rintf(v0.y * winv)) & 15;
  int n2 = ((int)rintf(v0.z * winv)) & 15;
  int n3 = ((int)rintf(v0.w * winv)) & 15;
  int n4 = ((int)rintf(v1.x * winv)) & 15;
  int n5 = ((int)rintf(v1.y * winv)) & 15;
  int n6 = ((int)rintf(v1.z * winv)) & 15;
  int n7 = ((int)rintf(v1.w * winv)) & 15;
  return n0 | (n1 << 4) | (n2 << 8) | (n3 << 12) | (n4 << 16) | (n5 << 20) |
         (n6 << 24) | (n7 << 28);
}

// ---------------- K1: input projection GEMM ----------------
__global__ __launch_bounds__(256) void zx_gemm(
    const int* __restrict__ sent, const float* __restrict__ embed,
    const float* __restrict__ Wih_f, const float* __restrict__ b_f,
    const float* __restrict__ Wih_b, const float* __restrict__ b_b,
    float* __restrict__ zxF, float* __restrict__ zxB)
{
  const int dir = blockIdx.y;
  const int t0 = blockIdx.x * 8;
  const float* __restrict__ Wih = dir ? Wih_b : Wih_f;
  const float* __restrict__ bias = dir ? b_b : b_f;
  float* __restrict__ zx = dir ? zxB : zxF;

  __shared__ __align__(16) float xs[8 * E_DIM];
  const int tid = threadIdx.x;
  for (int ti = 0; ti < 8; ++ti) {
    int p = t0 + ti;
    int tok = sent[dir ? (T_LEN - 1 - p) : p];
    const float* er = embed + (size_t)tok * E_DIM;
    for (int k = tid; k < E_DIM; k += 256) xs[ti * E_DIM + k] = er[k];
  }
  __syncthreads();

  const int r = tid;
  float acc[4][8];
#pragma unroll
  for (int g = 0; g < 4; ++g) {
    float bv = bias[g * 256 + r];
#pragma unroll
    for (int ti = 0; ti < 8; ++ti) acc[g][ti] = bv;
  }
  const float4* w0p = (const float4*)(Wih + (size_t)(r) * E_DIM);
  const float4* w1p = (const float4*)(Wih + (size_t)(256 + r) * E_DIM);
  const float4* w2p = (const float4*)(Wih + (size_t)(512 + r) * E_DIM);
  const float4* w3p = (const float4*)(Wih + (size_t)(768 + r) * E_DIM);
  for (int k4 = 0; k4 < E_DIM / 4; ++k4) {
    float4 w0 = w0p[k4], w1 = w1p[k4], w2 = w2p[k4], w3 = w3p[k4];
#pragma unroll
    for (int ti = 0; ti < 8; ++ti) {
      float4 x4 = *(const float4*)(xs + ti * E_DIM + k4 * 4);
      acc[0][ti] += w0.x * x4.x + w0.y * x4.y + w0.z * x4.z + w0.w * x4.w;
      acc[1][ti] += w1.x * x4.x + w1.y * x4.y + w1.z * x4.z + w1.w * x4.w;
      acc[2][ti] += w2.x * x4.x + w2.y * x4.y + w2.z * x4.z + w2.w * x4.w;
      acc[3][ti] += w3.x * x4.x + w3.y * x4.y + w3.z * x4.z + w3.w * x4.w;
    }
  }
#pragma unroll
  for (int g = 0; g < 4; ++g)
#pragma unroll
    for (int ti = 0; ti < 8; ++ti)
      zx[(size_t)(t0 + ti) * G4 + g * 256 + r] = acc[g][ti];
}

// ---------------- K2: int4 weight-stationary LSTM (sdot8) ----------------
__global__ __launch_bounds__(512, 2) void lstm_kernel(
    const float* __restrict__ Whh_f, const float* __restrict__ Whh_b,
    const float* __restrict__ h0, const float* __restrict__ c0,
    const float* __restrict__ zxF, const float* __restrict__ zxB,
    uint32_t* __restrict__ hhF, uint32_t* __restrict__ hhB)
{
  const int d = blockIdx.x;
  const float* __restrict__ Whh = d ? Whh_b : Whh_f;
  const float* __restrict__ zxd = d ? zxB : zxF;
  uint32_t* __restrict__ hh = d ? hhB : hhF;

  const int tid = threadIdx.x;
  const int l = tid & 3;   // k-slice AND my gate
  const int p = tid >> 2;  // elem pair 0..127 (elems 2p, 2p+1)

  __shared__ __align__(16) uint32_t hQA[32];   // int4-packed h, 128 B
  __shared__ __align__(16) uint32_t hQB[32];
  __shared__ __align__(16) uint32_t h8A[64];   // int8 staging for history, 256 B
  __shared__ __align__(16) uint32_t h8B[64];

  // ---- one-time: int4-quantize 8 rotated gate-rows (2 elems x 4 gates) ----
  // row m = grp*4+s -> global row ((l+s)&3)*256 + 2p+grp, k-slice
  // [l*64, l*64+64) -> 8 dwords (8 nibbles each, k ascending).
  int wq[64];
  float swA, swB;
#pragma unroll
  for (int grp = 0; grp < 2; ++grp) {
    int e = 2 * p + grp;
#pragma unroll
    for (int s = 0; s < 4; ++s) {
      int r = (l + s) & 3;
      const float4* Wr = (const float4*)(Whh + (size_t)(r * 256 + e) * H2);
      float amax = 1e-12f;
      for (int i = 0; i < 64; ++i) {  // full-row scan: scale consistent across slices
        float4 v = Wr[i];
        amax = fmaxf(amax, fmaxf(fmaxf(fabsf(v.x), fabsf(v.y)),
                                 fmaxf(fabsf(v.z), fabsf(v.w))));
      }
      const float winv = 7.f / amax;
      if (s == 0) { if (grp == 0) swA = amax / 7.f; else swB = amax / 7.f; }
      for (int dw = 0; dw < 8; ++dw) {
        float4 v0 = Wr[l * 16 + dw * 2];
        float4 v1 = Wr[l * 16 + dw * 2 + 1];
        wq[(grp * 4 + s) * 8 + dw] = packn(v0, v1, winv);
      }
    }
  }

  // ---- h0 scale (redundant scan) + int4 seed ----
  float h0max = 1e-12f;
  const float4* H0 = (const float4*)(h0 + d * H2);
  for (int i = 0; i < 64; ++i) {
    float4 v = H0[i];
    h0max = fmaxf(h0max, fmaxf(fmaxf(fabsf(v.x), fabsf(v.y)),
                               fmaxf(fabsf(v.z), fabsf(v.w))));
  }
  if (tid < 32) {  // dword tid covers elems 8*tid..8*tid+7
    float inv0 = 7.f / h0max;
    float4 v0 = H0[tid * 2];
    float4 v1 = H0[tid * 2 + 1];
    hQA[tid] = (uint32_t)packn(v0, v1, inv0);
  }

  const float sfA = swA * (h0max / 7.f), srA = swA * (1.f / 7.f);
  const float sfB = swB * (h0max / 7.f), srB = swB * (1.f / 7.f);
  const bool is_g = (l == 2);
  const bool is_i = (l == 0);

  float c0r = c0[d * H2 + 2 * p];      // live only in lane l==0
  float c1r = c0[d * H2 + 2 * p + 1];

  const float* zp = zxd + l * 256 + 2 * p;  // my gate's zx pair stream
  float2 zcur = *(const float2*)zp;
  uint32_t* hp = hh + tid;  // tid<64 stores int8 h history
  __syncthreads();

  auto step = [&](const uint32_t* hin, uint32_t* hout, uint32_t* h8out,
                  float sA, float sB) {
    float2 znext = *(const float2*)(zp + G4);  // prefetch t+1 (overread safe)

    // my k-slice of h: 2 b128 broadcast-group reads (8 dwords = 64 int4)
    uint32_t hd[8];
    *(uint4*)(hd) = *((const uint4*)hin + l * 2);
    *(uint4*)(hd + 4) = *((const uint4*)hin + l * 2 + 1);

    // 8 rotated rows x 8 sdot8
    int a0 = 0, a1 = 0, a2 = 0, a3 = 0, b0 = 0, b1 = 0, b2 = 0, b3 = 0;
#pragma unroll
    for (int i = 0; i < 8; ++i) {
      int hv = (int)hd[i];
      a0 = dot8(wq[i], hv, a0);
      a1 = dot8(wq[8 + i], hv, a1);
      a2 = dot8(wq[16 + i], hv, a2);
      a3 = dot8(wq[24 + i], hv, a3);
      b0 = dot8(wq[32 + i], hv, b0);
      b1 = dot8(wq[40 + i], hv, b1);
      b2 = dot8(wq[48 + i], hv, b2);
      b3 = dot8(wq[56 + i], hv, b3);
    }
    // rotate-reduce per elem group: lane g ends with gate g's full sum
    int totA = a0;
    totA += dppmovi<0x93>(a1);
    totA += dppmovi<0x4E>(a2);
    totA += dppmovi<0x39>(a3);
    int totB = b0;
    totB += dppmovi<0x93>(b1);
    totB += dppmovi<0x4E>(b2);
    totB += dppmovi<0x39>(b3);
    float zA = (float)totA * sA + zcur.x;
    float zB = (float)totB * sB + zcur.y;

    // distributed gate function (lane 2 = tanh via 2*sigmoid(2x)-1)
    float xA = is_g ? (zA + zA) : zA;
    float xB = is_g ? (zB + zB) : zB;
    float gA = fast_sigmoid(xA);
    float gB = fast_sigmoid(xB);
    float yA = is_g ? (gA + gA - 1.f) : gA;
    float yB = is_g ? (gB + gB - 1.f) : gB;

    // gather f,g,o into lane 0
    float pfA = dppmovf<0xB1>(yA), pgA = dppmovf<0x4E>(yA), poA = dppmovf<0x1B>(yA);
    float pfB = dppmovf<0xB1>(yB), pgB = dppmovf<0x4E>(yB), poB = dppmovf<0x1B>(yB);
    if (is_i) {
      c0r = pfA * c0r + yA * pgA;
      c1r = pfB * c1r + yB * pgB;
      float hv0 = poA * fast_tanh(c0r);
      float hv1 = poB * fast_tanh(c1r);
      // int4 for the recurrence exchange (byte p = nibbles of elems 2p,2p+1)
      int q0 = ((int)rintf(hv0 * 7.f)) & 15;
      int q1 = ((int)rintf(hv1 * 7.f)) & 15;
      ((unsigned char*)hout)[p] = (unsigned char)(q0 | (q1 << 4));
      // int8 for the history (feats quality unchanged)
      int s0 = ((int)rintf(hv0 * 127.f)) & 255;
      int s1 = ((int)rintf(hv1 * 127.f)) & 255;
      ((uint16_t*)h8out)[p] = (uint16_t)(s0 | (s1 << 8));
    }
    zcur = znext;
    zp += G4;
    // barrier WITHOUT vmcnt drain: LDS ordering only; zx prefetch in flight
    asm volatile("s_waitcnt lgkmcnt(0)\n\ts_barrier" ::: "memory");
    if (tid < 64) *hp = h8out[tid];  // int8 h history (wave 0 only)
    hp += 64;
  };

  step(hQA, hQB, h8B, sfA, sfB);
  step(hQB, hQA, h8A, srA, srB);
  for (int t = 2; t < T_LEN; t += 2) {
    step(hQA, hQB, h8B, srA, srB);
    step(hQB, hQA, h8A, srA, srB);
  }
}

// ---------------- K3: feats = [hf|hb] @ W_out^T + b_out ----------------
__global__ __launch_bounds__(256) void feat_kernel(
    const uint32_t* __restrict__ hhF, const uint32_t* __restrict__ hhB,
    const float* __restrict__ W_out, const float* __restrict__ b_out,
    float* __restrict__ feats)
{
  const int p0 = blockIdx.x * 8;
  const int tid = threadIdx.x;
  __shared__ float hs[8 * 520];
#define HIDX(pos, k) ((pos) * 520 + (k) + ((k) >> 6))
  const float s = 1.f / 127.f;
  for (int idx = tid; idx < 512; idx += 256) {  // 8 pos x 64 dwords
    int pos = idx >> 6, dw = idx & 63;
    uint32_t vf = hhF[(size_t)(p0 + pos) * 64 + dw];
    uint32_t vb = hhB[(size_t)(T_LEN - 1 - (p0 + pos)) * 64 + dw];
    int k = dw * 4;
    hs[HIDX(pos, k + 0)] = (float)(int8_t)(vf) * s;
    hs[HIDX(pos, k + 1)] = (float)(int8_t)(vf >> 8) * s;
    hs[HIDX(pos, k + 2)] = (float)(int8_t)(vf >> 16) * s;
    hs[HIDX(pos, k + 3)] = (float)(int8_t)(vf >> 24) * s;
    int kb = 256 + k;
    hs[HIDX(pos, kb + 0)] = (float)(int8_t)(vb) * s;
    hs[HIDX(pos, kb + 1)] = (float)(int8_t)(vb >> 8) * s;
    hs[HIDX(pos, kb + 2)] = (float)(int8_t)(vb >> 16) * s;
    hs[HIDX(pos, kb + 3)] = (float)(int8_t)(vb >> 24) * s;
  }
  __syncthreads();

  const int tag = tid >> 3;
  const int kc = tid & 7;
  float4 w4[16];
  const float4* wp = (const float4*)(W_out + tag * 512 + kc * 64);
#pragma unroll
  for (int i = 0; i < 16; ++i) w4[i] = wp[i];
  const float bo = b_out[tag];

#pragma unroll
  for (int pos = 0; pos < 8; ++pos) {
    const float* hpp = hs + pos * 520 + kc * 64 + kc;
    float a = 0.f;
#pragma unroll
    for (int i = 0; i < 16; ++i) {
      float4 w = w4[i];
      a += w.x * hpp[i * 4] + w.y * hpp[i * 4 + 1] + w.z * hpp[i * 4 + 2] + w.w * hpp[i * 4 + 3];
    }
    a += __shfl_xor(a, 1);
    a += __shfl_xor(a, 2);
    a += __shfl_xor(a, 4);
    if (kc == 0) feats[(size_t)(p0 + pos) * KTAGS + tag] = a + bo;
  }
}

// ---------------- K4a: parallel chunk transfer matrices ----------------
__global__ __launch_bounds__(1024) void vit_phaseA(
    const float* __restrict__ feats, const float* __restrict__ trans,
    float* __restrict__ Cmat)
{
  const int c = blockIdx.x;
  const int tid = threadIdx.x;
  const int i = tid >> 5, j = tid & 31;
  const int t0 = c * CLEN;

  float Trow[32];
#pragma unroll
  for (int k = 0; k < 32; ++k) Trow[k] = trans[i * 32 + k];

  __shared__ float Ca[1024], Cb[1024];
  Ca[tid] = Trow[j] + feats[(size_t)t0 * KTAGS + i];
  __syncthreads();

  float* cur = Ca;
  float* nxt = Cb;
  for (int s = 1; s < CLEN; ++s) {
    float fi = feats[(size_t)(t0 + s) * KTAGS + i];
    float m = Trow[0] + cur[j];
#pragma unroll
    for (int k = 1; k < 32; ++k) m = fmaxf(m, Trow[k] + cur[k * 32 + j]);
    nxt[tid] = m + fi;
    __syncthreads();
    float* tmp = cur; cur = nxt; nxt = tmp;
  }
  Cmat[(size_t)c * 1024 + tid] = cur[tid];
}

// ---------------- K4b: sequential chunk-level pass (tiny) ----------------
__global__ __launch_bounds__(64) void vit_phaseB(
    const float* __restrict__ Cmat, const float* __restrict__ trans,
    float* __restrict__ fvs, float* __restrict__ score_out,
    int* __restrict__ best_out)
{
  const int ln = threadIdx.x;
  const int i = ln & 31;
  float fv = (i == START_TAG) ? 0.0f : NEGV;
  if (ln < 32) fvs[i] = fv;

  for (int c = 0; c < NCHUNK; ++c) {
    const float* Crow = Cmat + (size_t)c * 1024 + i * 32;
    float cr[32];
#pragma unroll
    for (int w = 0; w < 8; ++w) *(float4*)(cr + 4 * w) = *(const float4*)(Crow + 4 * w);
    float m = cr[0] + __shfl(fv, 0);
#pragma unroll
    for (int jj = 1; jj < 32; ++jj) m = fmaxf(m, cr[jj] + __shfl(fv, jj));
    fv = m;
    if (ln < 32) fvs[(c + 1) * 32 + i] = fv;
  }

  float v = fv + trans[STOP_TAG * 32 + i];
  int bi = i;
#pragma unroll
  for (int m = 1; m < 32; m <<= 1) {
    float ov = __shfl_xor(v, m);
    int oi = __shfl_xor(bi, m);
    if (ov > v || (ov == v && oi < bi)) { v = ov; bi = oi; }
  }
  if (ln == 0) { score_out[0] = v; best_out[0] = bi; }
}

// ---------------- K4c: parallel per-chunk bptr regeneration ----------------
__global__ __launch_bounds__(64) void vit_phaseC(
    const float* __restrict__ feats, const float* __restrict__ trans,
    const float* __restrict__ fvs, unsigned char* __restrict__ bptr)
{
  const int c = blockIdx.x;
  const int ln = threadIdx.x;
  const int i = ln & 31;
  const int jb = ln >> 5;
  const int t0 = c * CLEN;

  float Tj[16];
#pragma unroll
  for (int s = 0; s < 16; ++s) Tj[s] = trans[i * 32 + jb * 16 + s];

  float fv = fvs[c * 32 + i];
  float pf = feats[(size_t)t0 * KTAGS + i];

  for (int s = 0; s < CLEN; ++s) {
    float cv[16];
    int cj[16];
#pragma unroll
    for (int ss = 0; ss < 16; ++ss) {
      cv[ss] = __shfl(fv, jb * 16 + ss) + Tj[ss];
      cj[ss] = jb * 16 + ss;
    }
#pragma unroll
    for (int st = 1; st < 16; st <<= 1)
#pragma unroll
      for (int ss = 0; ss < 16; ss += 2 * st)
        if (cv[ss + st] > cv[ss]) { cv[ss] = cv[ss + st]; cj[ss] = cj[ss + st]; }
    float v = cv[0];
    int bj = cj[0];
    float ov = __shfl_xor(v, 32);
    int oj = __shfl_xor(bj, 32);
    if (ov > v || (ov == v && oj < bj)) { v = ov; bj = oj; }

    int t = t0 + s;
    float f = pf;
    int tn = (t + 1 < T_LEN) ? t + 1 : t;
    pf = feats[(size_t)tn * KTAGS + i];
    fv = v + f;
    if (jb == 0) bptr[(size_t)t * KTAGS + i] = (unsigned char)bj;
  }
}

// ---------------- K5: compose 32-step backtrace maps ----------------
__global__ __launch_bounds__(64) void vit_compose(
    const unsigned char* __restrict__ bptr, unsigned char* __restrict__ fmap)
{
  const int m = blockIdx.x;
  __shared__ unsigned char B[32 * 32];
  const int tid = threadIdx.x;
  const uint32_t* src = (const uint32_t*)(bptr + (size_t)m * 1024);
  uint32_t* dstw = (uint32_t*)B;
  for (int idx = tid; idx < 256; idx += 64) dstw[idx] = src[idx];
  __syncthreads();
  if (tid < 32) {
    int y = tid;
#pragma unroll
    for (int tt = 31; tt >= 0; --tt) y = B[tt * 32 + y];
    fmap[m * 32 + tid] = (unsigned char)y;
  }
}

// ---------------- K6: boundary walk + parallel expansion ----------------
__global__ __launch_bounds__(256) void vit_backtrace(
    const unsigned char* __restrict__ bptr, const unsigned char* __restrict__ fmap,
    const int* __restrict__ best, float* __restrict__ path_out)
{
  __shared__ unsigned char F[128 * 32];
  __shared__ unsigned char bound[128];
  const int tid = threadIdx.x;
  const uint32_t* src = (const uint32_t*)fmap;
  uint32_t* dstw = (uint32_t*)F;
  for (int idx = tid; idx < 1024; idx += 256) dstw[idx] = src[idx];
  __syncthreads();
  if (tid == 0) {
    int y = best[0];
    bound[127] = (unsigned char)y;
    for (int m = 127; m >= 1; --m) {
      y = F[m * 32 + y];
      bound[m - 1] = (unsigned char)y;
    }
  }
  __syncthreads();
  if (tid < 128) {
    const int m = tid;
    int y = bound[m];
    path_out[m * 32 + 31] = (float)y;
    for (int tt = 30; tt >= 0; --tt) {
      y = bptr[(size_t)(m * 32 + tt + 1) * 32 + y];
      path_out[m * 32 + tt] = (float)y;
    }
  }
}

extern "C" void kernel_launch(void* const* d_in, const int* in_sizes, int n_in,
                              void* d_out, int out_size, void* d_ws, size_t ws_size,
                              hipStream_t stream)
{
  const int* sent    = (const int*)d_in[0];
  const float* embed = (const float*)d_in[1];
  const float* Wih_f = (const float*)d_in[2];
  const float* Whh_f = (const float*)d_in[3];
  const float* b_f   = (const float*)d_in[4];
  const float* Wih_b = (const float*)d_in[5];
  const float* Whh_b = (const float*)d_in[6];
  const float* b_b   = (const float*)d_in[7];
  const float* W_out = (const float*)d_in[8];
  const float* b_out = (const float*)d_in[9];
  const float* trans = (const float*)d_in[10];
  const float* h0    = (const float*)d_in[11];
  const float* c0    = (const float*)d_in[12];

  float* W = (float*)d_ws;
  float* zxF = W;                                    // 16 MB (dead after lstm)
  float* zxB = zxF + (size_t)T_LEN * G4;             // 16 MB
  float* feats = zxB + (size_t)T_LEN * G4;           // 512 KB
  uint32_t* hhF = (uint32_t*)(feats + (size_t)T_LEN * KTAGS);  // 1 MB (int8 h)
  uint32_t* hhB = hhF + (size_t)T_LEN * 64;          // 1 MB
  int* bestIdx = (int*)(hhB + (size_t)T_LEN * 64);
  unsigned char* bptr = (unsigned char*)(bestIdx + 16);  // 128 KB
  unsigned char* fmap = bptr + (size_t)T_LEN * KTAGS;    // 4 KB
  float* Cmat = zxF;                                 // overlay, 512 KB
  float* fvs = zxF + NCHUNK * 1024;                  // 129*32 floats

  float* out = (float*)d_out;  // out[0]=path_score, out[1..4096]=path tags

  zx_gemm<<<dim3(T_LEN / 8, 2), 256, 0, stream>>>(sent, embed, Wih_f, b_f, Wih_b, b_b, zxF, zxB);
  lstm_kernel<<<2, 512, 0, stream>>>(Whh_f, Whh_b, h0, c0, zxF, zxB, hhF, hhB);
  feat_kernel<<<T_LEN / 8, 256, 0, stream>>>(hhF, hhB, W_out, b_out, feats);
  vit_phaseA<<<NCHUNK, 1024, 0, stream>>>(feats, trans, Cmat);
  vit_phaseB<<<1, 64, 0, stream>>>(Cmat, trans, fvs, out, bestIdx);
  vit_phaseC<<<NCHUNK, 64, 0, stream>>>(feats, trans, fvs, bptr);
  vit_compose<<<128, 64, 0, stream>>>(bptr, fmap);
  vit_backtrace<<<1, 256, 0, stream>>>(bptr, fmap, bestIdx, out + 1);
}

// Round 11
// 3178.449 us; speedup vs baseline: 1.3390x; 1.0615x over previous
//
#include <hip/hip_runtime.h>
#include <hip/hip_bf16.h>
#include <cstdint>
#include <cstddef>

// BiLSTM-CRF forward + Viterbi decode, T=4096, E=300, H2=256, K=32.
//   K1 zx_gemm    : zx[t] = Wih @ embed[token] + b (both dirs, batched)
//   K2 lstm_kernel: one CU per direction, 512 thr @ (512,2), int4 weights +
//                   v_dot8_i32_i4 (R10: dot floor 512 cy/SIMD/step, confirmed
//                   by the exact 0.88ms R9->R10 delta). R11 trims the ~670cy
//                   non-dot issue: (a) h history stored DIRECTLY to global
//                   from the gate lane (h8 LDS staging + wave0 copy removed),
//                   (b) gate algebra via hoisted per-lane constants
//                   x=z*xm, y=fma(sg,ya,yb) — no in-loop selects.
//   K3 feat_kernel: feats = [hf|hb] @ W_out^T + b_out (unpack int8 h)
//   K4a vit_phaseA: parallel 32-step max-plus chunk matrices
//   K4b vit_phaseB: sequential chunk-level pass (double-buffered loads)
//   K4c vit_phaseC: per-chunk bptr regen + FUSED 32-step map composition
//   K6 vit_backtrace: boundary walk + parallel expansion.

#define T_LEN 4096
#define E_DIM 300
#define H2 256
#define G4 1024
#define KTAGS 32
#define START_TAG 30
#define STOP_TAG 31
#define NEGV (-10000.0f)
#define NCHUNK 128
#define CLEN 32

#if defined(__has_builtin)
#if __has_builtin(__builtin_amdgcn_sdot8)
#define HAVE_SDOT8 1
#endif
#endif
#ifndef HAVE_SDOT8
#define HAVE_SDOT8 0
#endif

__device__ __forceinline__ int dot8(int a, int b, int c) {
#if HAVE_SDOT8
  return __builtin_amdgcn_sdot8(a, b, c, false);
#else
  int r = c;
#pragma unroll
  for (int i = 0; i < 8; ++i) {
    int an = (a << (28 - 4 * i)) >> 28;
    int bn = (b << (28 - 4 * i)) >> 28;
    r += an * bn;
  }
  return r;
#endif
}

__device__ __forceinline__ float fast_sigmoid(float x) {
  return __builtin_amdgcn_rcpf(1.0f + __expf(-x));
}
__device__ __forceinline__ float fast_tanh(float x) {
  return 1.0f - 2.0f * __builtin_amdgcn_rcpf(__expf(2.0f * x) + 1.0f);
}

template <int CTRL>
__device__ __forceinline__ float dppmovf(float x) {
  return __int_as_float(
      __builtin_amdgcn_update_dpp(0, __float_as_int(x), CTRL, 0xF, 0xF, true));
}
template <int CTRL>
__device__ __forceinline__ int dppmovi(int x) {
  return __builtin_amdgcn_update_dpp(0, x, CTRL, 0xF, 0xF, true);
}

// pack 8 consecutive weights (two float4) into one int4x8 dword
__device__ __forceinline__ int packn(float4 v0, float4 v1, float winv) {
  int n0 = ((int)rintf(v0.x * winv)) & 15;
  int n1 = ((int)rintf(v0.y * winv)) & 15;
  int n2 = ((int)rintf(v0.z * winv)) & 15;
  int n3 = ((int)rintf(v0.w * winv)) & 15;
  int n4 = ((int)rintf(v1.x * winv)) & 15;
  int n5 = ((int)rintf(v1.y * winv)) & 15;
  int n6 = ((int)rintf(v1.z * winv)) & 15;
  int n7 = ((int)rintf(v1.w * winv)) & 15;
  return n0 | (n1 << 4) | (n2 << 8) | (n3 << 12) | (n4 << 16) | (n5 << 20) |
         (n6 << 24) | (n7 << 28);
}

// ---------------- K1: input projection GEMM ----------------
__global__ __launch_bounds__(256) void zx_gemm(
    const int* __restrict__ sent, const float* __restrict__ embed,
    const float* __restrict__ Wih_f, const float* __restrict__ b_f,
    const float* __restrict__ Wih_b, const float* __restrict__ b_b,
    float* __restrict__ zxF, float* __restrict__ zxB)
{
  const int dir = blockIdx.y;
  const int t0 = blockIdx.x * 8;
  const float* __restrict__ Wih = dir ? Wih_b : Wih_f;
  const float* __restrict__ bias = dir ? b_b : b_f;
  float* __restrict__ zx = dir ? zxB : zxF;

  __shared__ __align__(16) float xs[8 * E_DIM];
  const int tid = threadIdx.x;
  for (int ti = 0; ti < 8; ++ti) {
    int p = t0 + ti;
    int tok = sent[dir ? (T_LEN - 1 - p) : p];
    const float* er = embed + (size_t)tok * E_DIM;
    for (int k = tid; k < E_DIM; k += 256) xs[ti * E_DIM + k] = er[k];
  }
  __syncthreads();

  const int r = tid;
  float acc[4][8];
#pragma unroll
  for (int g = 0; g < 4; ++g) {
    float bv = bias[g * 256 + r];
#pragma unroll
    for (int ti = 0; ti < 8; ++ti) acc[g][ti] = bv;
  }
  const float4* w0p = (const float4*)(Wih + (size_t)(r) * E_DIM);
  const float4* w1p = (const float4*)(Wih + (size_t)(256 + r) * E_DIM);
  const float4* w2p = (const float4*)(Wih + (size_t)(512 + r) * E_DIM);
  const float4* w3p = (const float4*)(Wih + (size_t)(768 + r) * E_DIM);
  for (int k4 = 0; k4 < E_DIM / 4; ++k4) {
    float4 w0 = w0p[k4], w1 = w1p[k4], w2 = w2p[k4], w3 = w3p[k4];
#pragma unroll
    for (int ti = 0; ti < 8; ++ti) {
      float4 x4 = *(const float4*)(xs + ti * E_DIM + k4 * 4);
      acc[0][ti] += w0.x * x4.x + w0.y * x4.y + w0.z * x4.z + w0.w * x4.w;
      acc[1][ti] += w1.x * x4.x + w1.y * x4.y + w1.z * x4.z + w1.w * x4.w;
      acc[2][ti] += w2.x * x4.x + w2.y * x4.y + w2.z * x4.z + w2.w * x4.w;
      acc[3][ti] += w3.x * x4.x + w3.y * x4.y + w3.z * x4.z + w3.w * x4.w;
    }
  }
#pragma unroll
  for (int g = 0; g < 4; ++g)
#pragma unroll
    for (int ti = 0; ti < 8; ++ti)
      zx[(size_t)(t0 + ti) * G4 + g * 256 + r] = acc[g][ti];
}

// ---------------- K2: int4 weight-stationary LSTM (sdot8, trimmed) ----------
__global__ __launch_bounds__(512, 2) void lstm_kernel(
    const float* __restrict__ Whh_f, const float* __restrict__ Whh_b,
    const float* __restrict__ h0, const float* __restrict__ c0,
    const float* __restrict__ zxF, const float* __restrict__ zxB,
    uint32_t* __restrict__ hhF, uint32_t* __restrict__ hhB)
{
  const int d = blockIdx.x;
  const float* __restrict__ Whh = d ? Whh_b : Whh_f;
  const float* __restrict__ zxd = d ? zxB : zxF;
  uint32_t* __restrict__ hh = d ? hhB : hhF;

  const int tid = threadIdx.x;
  const int l = tid & 3;   // k-slice AND my gate
  const int p = tid >> 2;  // elem pair 0..127 (elems 2p, 2p+1)

  __shared__ __align__(16) uint32_t hQA[32];   // int4-packed h, 128 B
  __shared__ __align__(16) uint32_t hQB[32];

  // ---- one-time: int4-quantize 8 rotated gate-rows (2 elems x 4 gates) ----
  int wq[64];
  float swA, swB;
#pragma unroll
  for (int grp = 0; grp < 2; ++grp) {
    int e = 2 * p + grp;
#pragma unroll
    for (int s = 0; s < 4; ++s) {
      int r = (l + s) & 3;
      const float4* Wr = (const float4*)(Whh + (size_t)(r * 256 + e) * H2);
      float amax = 1e-12f;
      for (int i = 0; i < 64; ++i) {  // full-row scan: scale consistent across slices
        float4 v = Wr[i];
        amax = fmaxf(amax, fmaxf(fmaxf(fabsf(v.x), fabsf(v.y)),
                                 fmaxf(fabsf(v.z), fabsf(v.w))));
      }
      const float winv = 7.f / amax;
      if (s == 0) { if (grp == 0) swA = amax / 7.f; else swB = amax / 7.f; }
      for (int dw = 0; dw < 8; ++dw) {
        float4 v0 = Wr[l * 16 + dw * 2];
        float4 v1 = Wr[l * 16 + dw * 2 + 1];
        wq[(grp * 4 + s) * 8 + dw] = packn(v0, v1, winv);
      }
    }
  }

  // ---- h0 scale (redundant scan) + int4 seed ----
  float h0max = 1e-12f;
  const float4* H0 = (const float4*)(h0 + d * H2);
  for (int i = 0; i < 64; ++i) {
    float4 v = H0[i];
    h0max = fmaxf(h0max, fmaxf(fmaxf(fabsf(v.x), fabsf(v.y)),
                               fmaxf(fabsf(v.z), fabsf(v.w))));
  }
  if (tid < 32) {
    float inv0 = 7.f / h0max;
    float4 v0 = H0[tid * 2];
    float4 v1 = H0[tid * 2 + 1];
    hQA[tid] = (uint32_t)packn(v0, v1, inv0);
  }

  const float sfA = swA * (h0max / 7.f), srA = swA * (1.f / 7.f);
  const float sfB = swB * (h0max / 7.f), srB = swB * (1.f / 7.f);
  const bool is_i = (l == 0);
  // hoisted gate-algebra constants: x = z*xm ; y = fma(sigmoid(x), ya, yb)
  const float xm = (l == 2) ? 2.f : 1.f;
  const float ya = (l == 2) ? 2.f : 1.f;
  const float yb = (l == 2) ? -1.f : 0.f;

  float c0r = c0[d * H2 + 2 * p];      // live only in lane l==0
  float c1r = c0[d * H2 + 2 * p + 1];

  const float* zp = zxd + l * 256 + 2 * p;  // my gate's zx pair stream
  float2 zcur = *(const float2*)zp;
  uint16_t* hw = (uint16_t*)hh + p;  // direct history stream (is_i lane)
  __syncthreads();

  auto step = [&](const uint32_t* hin, uint32_t* hout, float sA, float sB) {
    float2 znext = *(const float2*)(zp + G4);  // prefetch t+1 (overread safe)

    // my k-slice of h: 2 b128 broadcast-group reads (8 dwords = 64 int4)
    uint32_t hd[8];
    *(uint4*)(hd) = *((const uint4*)hin + l * 2);
    *(uint4*)(hd + 4) = *((const uint4*)hin + l * 2 + 1);

    // 8 rotated rows x 8 sdot8
    int a0 = 0, a1 = 0, a2 = 0, a3 = 0, b0 = 0, b1 = 0, b2 = 0, b3 = 0;
#pragma unroll
    for (int i = 0; i < 8; ++i) {
      int hv = (int)hd[i];
      a0 = dot8(wq[i], hv, a0);
      a1 = dot8(wq[8 + i], hv, a1);
      a2 = dot8(wq[16 + i], hv, a2);
      a3 = dot8(wq[24 + i], hv, a3);
      b0 = dot8(wq[32 + i], hv, b0);
      b1 = dot8(wq[40 + i], hv, b1);
      b2 = dot8(wq[48 + i], hv, b2);
      b3 = dot8(wq[56 + i], hv, b3);
    }
    // rotate-reduce per elem group: lane g ends with gate g's full sum
    int totA = a0;
    totA += dppmovi<0x93>(a1);
    totA += dppmovi<0x4E>(a2);
    totA += dppmovi<0x39>(a3);
    int totB = b0;
    totB += dppmovi<0x93>(b1);
    totB += dppmovi<0x4E>(b2);
    totB += dppmovi<0x39>(b3);
    float zA = (float)totA * sA + zcur.x;
    float zB = (float)totB * sB + zcur.y;

    // gate function, select-free (xm/ya/yb hoisted)
    float yA = fast_sigmoid(zA * xm) * ya + yb;
    float yB = fast_sigmoid(zB * xm) * ya + yb;

    // gather f,g,o into lane 0
    float pfA = dppmovf<0xB1>(yA), pgA = dppmovf<0x4E>(yA), poA = dppmovf<0x1B>(yA);
    float pfB = dppmovf<0xB1>(yB), pgB = dppmovf<0x4E>(yB), poB = dppmovf<0x1B>(yB);
    if (is_i) {
      c0r = pfA * c0r + yA * pgA;
      c1r = pfB * c1r + yB * pgB;
      float hv0 = poA * fast_tanh(c0r);
      float hv1 = poB * fast_tanh(c1r);
      // int4 recurrence exchange
      int q0 = ((int)rintf(hv0 * 7.f)) & 15;
      int q1 = ((int)rintf(hv1 * 7.f)) & 15;
      ((unsigned char*)hout)[p] = (unsigned char)(q0 | (q1 << 4));
      // int8 history: DIRECT global store (no LDS staging, no wave0 copy;
      // barrier below doesn't drain vmcnt, so this stays in flight)
      int s0 = ((int)rintf(hv0 * 127.f)) & 255;
      int s1 = ((int)rintf(hv1 * 127.f)) & 255;
      *hw = (uint16_t)(s0 | (s1 << 8));
    }
    hw += 128;
    zcur = znext;
    zp += G4;
    // barrier WITHOUT vmcnt drain: LDS ordering only
    asm volatile("s_waitcnt lgkmcnt(0)\n\ts_barrier" ::: "memory");
  };

  step(hQA, hQB, sfA, sfB);
  step(hQB, hQA, srA, srB);
  for (int t = 2; t < T_LEN; t += 2) {
    step(hQA, hQB, srA, srB);
    step(hQB, hQA, srA, srB);
  }
}

// ---------------- K3: feats = [hf|hb] @ W_out^T + b_out ----------------
__global__ __launch_bounds__(256) void feat_kernel(
    const uint32_t* __restrict__ hhF, const uint32_t* __restrict__ hhB,
    const float* __restrict__ W_out, const float* __restrict__ b_out,
    float* __restrict__ feats)
{
  const int p0 = blockIdx.x * 8;
  const int tid = threadIdx.x;
  __shared__ float hs[8 * 520];
#define HIDX(pos, k) ((pos) * 520 + (k) + ((k) >> 6))
  const float s = 1.f / 127.f;
  for (int idx = tid; idx < 512; idx += 256) {  // 8 pos x 64 dwords
    int pos = idx >> 6, dw = idx & 63;
    uint32_t vf = hhF[(size_t)(p0 + pos) * 64 + dw];
    uint32_t vb = hhB[(size_t)(T_LEN - 1 - (p0 + pos)) * 64 + dw];
    int k = dw * 4;
    hs[HIDX(pos, k + 0)] = (float)(int8_t)(vf) * s;
    hs[HIDX(pos, k + 1)] = (float)(int8_t)(vf >> 8) * s;
    hs[HIDX(pos, k + 2)] = (float)(int8_t)(vf >> 16) * s;
    hs[HIDX(pos, k + 3)] = (float)(int8_t)(vf >> 24) * s;
    int kb = 256 + k;
    hs[HIDX(pos, kb + 0)] = (float)(int8_t)(vb) * s;
    hs[HIDX(pos, kb + 1)] = (float)(int8_t)(vb >> 8) * s;
    hs[HIDX(pos, kb + 2)] = (float)(int8_t)(vb >> 16) * s;
    hs[HIDX(pos, kb + 3)] = (float)(int8_t)(vb >> 24) * s;
  }
  __syncthreads();

  const int tag = tid >> 3;
  const int kc = tid & 7;
  float4 w4[16];
  const float4* wp = (const float4*)(W_out + tag * 512 + kc * 64);
#pragma unroll
  for (int i = 0; i < 16; ++i) w4[i] = wp[i];
  const float bo = b_out[tag];

#pragma unroll
  for (int pos = 0; pos < 8; ++pos) {
    const float* hpp = hs + pos * 520 + kc * 64 + kc;
    float a = 0.f;
#pragma unroll
    for (int i = 0; i < 16; ++i) {
      float4 w = w4[i];
      a += w.x * hpp[i * 4] + w.y * hpp[i * 4 + 1] + w.z * hpp[i * 4 + 2] + w.w * hpp[i * 4 + 3];
    }
    a += __shfl_xor(a, 1);
    a += __shfl_xor(a, 2);
    a += __shfl_xor(a, 4);
    if (kc == 0) feats[(size_t)(p0 + pos) * KTAGS + tag] = a + bo;
  }
}

// ---------------- K4a: parallel chunk transfer matrices ----------------
__global__ __launch_bounds__(1024) void vit_phaseA(
    const float* __restrict__ feats, const float* __restrict__ trans,
    float* __restrict__ Cmat)
{
  const int c = blockIdx.x;
  const int tid = threadIdx.x;
  const int i = tid >> 5, j = tid & 31;
  const int t0 = c * CLEN;

  float Trow[32];
#pragma unroll
  for (int k = 0; k < 32; ++k) Trow[k] = trans[i * 32 + k];

  __shared__ float Ca[1024], Cb[1024];
  Ca[tid] = Trow[j] + feats[(size_t)t0 * KTAGS + i];
  __syncthreads();

  float* cur = Ca;
  float* nxt = Cb;
  for (int s = 1; s < CLEN; ++s) {
    float fi = feats[(size_t)(t0 + s) * KTAGS + i];
    float m = Trow[0] + cur[j];
#pragma unroll
    for (int k = 1; k < 32; ++k) m = fmaxf(m, Trow[k] + cur[k * 32 + j]);
    nxt[tid] = m + fi;
    __syncthreads();
    float* tmp = cur; cur = nxt; nxt = tmp;
  }
  Cmat[(size_t)c * 1024 + tid] = cur[tid];
}

// ---------------- K4b: sequential chunk-level pass (double-buffered) --------
__global__ __launch_bounds__(64) void vit_phaseB(
    const float* __restrict__ Cmat, const float* __restrict__ trans,
    float* __restrict__ fvs, float* __restrict__ score_out,
    int* __restrict__ best_out)
{
  const int ln = threadIdx.x;
  const int i = ln & 31;
  float fv = (i == START_TAG) ? 0.0f : NEGV;
  if (ln < 32) fvs[i] = fv;

  float cr[32], nx[32];
#pragma unroll
  for (int w = 0; w < 8; ++w)
    *(float4*)(cr + 4 * w) = *(const float4*)(Cmat + (size_t)i * 32 + 4 * w);

  for (int c = 0; c < NCHUNK; ++c) {
    if (c + 1 < NCHUNK) {  // prefetch next chunk row
      const float* Crow = Cmat + (size_t)(c + 1) * 1024 + i * 32;
#pragma unroll
      for (int w = 0; w < 8; ++w) *(float4*)(nx + 4 * w) = *(const float4*)(Crow + 4 * w);
    }
    float m = cr[0] + __shfl(fv, 0);
#pragma unroll
    for (int jj = 1; jj < 32; ++jj) m = fmaxf(m, cr[jj] + __shfl(fv, jj));
    fv = m;
    if (ln < 32) fvs[(c + 1) * 32 + i] = fv;
#pragma unroll
    for (int w = 0; w < 32; ++w) cr[w] = nx[w];
  }

  float v = fv + trans[STOP_TAG * 32 + i];
  int bi = i;
#pragma unroll
  for (int m = 1; m < 32; m <<= 1) {
    float ov = __shfl_xor(v, m);
    int oi = __shfl_xor(bi, m);
    if (ov > v || (ov == v && oi < bi)) { v = ov; bi = oi; }
  }
  if (ln == 0) { score_out[0] = v; best_out[0] = bi; }
}

// ---------------- K4c: bptr regen + fused chunk-map composition -------------
__global__ __launch_bounds__(64) void vit_phaseC(
    const float* __restrict__ feats, const float* __restrict__ trans,
    const float* __restrict__ fvs, unsigned char* __restrict__ bptr,
    unsigned char* __restrict__ fmap)
{
  const int c = blockIdx.x;
  const int ln = threadIdx.x;
  const int i = ln & 31;
  const int jb = ln >> 5;
  const int t0 = c * CLEN;

  __shared__ unsigned char B[CLEN * 32];

  float Tj[16];
#pragma unroll
  for (int s = 0; s < 16; ++s) Tj[s] = trans[i * 32 + jb * 16 + s];

  float fv = fvs[c * 32 + i];
  float pf = feats[(size_t)t0 * KTAGS + i];

  for (int s = 0; s < CLEN; ++s) {
    float cv[16];
    int cj[16];
#pragma unroll
    for (int ss = 0; ss < 16; ++ss) {
      cv[ss] = __shfl(fv, jb * 16 + ss) + Tj[ss];
      cj[ss] = jb * 16 + ss;
    }
#pragma unroll
    for (int st = 1; st < 16; st <<= 1)
#pragma unroll
      for (int ss = 0; ss < 16; ss += 2 * st)
        if (cv[ss + st] > cv[ss]) { cv[ss] = cv[ss + st]; cj[ss] = cj[ss + st]; }
    float v = cv[0];
    int bj = cj[0];
    float ov = __shfl_xor(v, 32);
    int oj = __shfl_xor(bj, 32);
    if (ov > v || (ov == v && oj < bj)) { v = ov; bj = oj; }

    int t = t0 + s;
    float f = pf;
    int tn = (t + 1 < T_LEN) ? t + 1 : t;
    pf = feats[(size_t)tn * KTAGS + i];
    fv = v + f;
    if (jb == 0) {
      bptr[(size_t)t * KTAGS + i] = (unsigned char)bj;
      B[s * 32 + i] = (unsigned char)bj;
    }
  }
  __syncthreads();
  if (ln < 32) {  // fused composition: tag@(t0+31) -> tag@(t0-1)
    int y = ln;
#pragma unroll
    for (int tt = CLEN - 1; tt >= 0; --tt) y = B[tt * 32 + y];
    fmap[c * 32 + ln] = (unsigned char)y;
  }
}

// ---------------- K6: boundary walk + parallel expansion ----------------
__global__ __launch_bounds__(256) void vit_backtrace(
    const unsigned char* __restrict__ bptr, const unsigned char* __restrict__ fmap,
    const int* __restrict__ best, float* __restrict__ path_out)
{
  __shared__ unsigned char F[128 * 32];
  __shared__ unsigned char bound[128];
  const int tid = threadIdx.x;
  const uint32_t* src = (const uint32_t*)fmap;
  uint32_t* dstw = (uint32_t*)F;
  for (int idx = tid; idx < 1024; idx += 256) dstw[idx] = src[idx];
  __syncthreads();
  if (tid == 0) {
    int y = best[0];
    bound[127] = (unsigned char)y;
    for (int m = 127; m >= 1; --m) {
      y = F[m * 32 + y];
      bound[m - 1] = (unsigned char)y;
    }
  }
  __syncthreads();
  if (tid < 128) {
    const int m = tid;
    int y = bound[m];
    path_out[m * 32 + 31] = (float)y;
    for (int tt = 30; tt >= 0; --tt) {
      y = bptr[(size_t)(m * 32 + tt + 1) * 32 + y];
      path_out[m * 32 + tt] = (float)y;
    }
  }
}

extern "C" void kernel_launch(void* const* d_in, const int* in_sizes, int n_in,
                              void* d_out, int out_size, void* d_ws, size_t ws_size,
                              hipStream_t stream)
{
  const int* sent    = (const int*)d_in[0];
  const float* embed = (const float*)d_in[1];
  const float* Wih_f = (const float*)d_in[2];
  const float* Whh_f = (const float*)d_in[3];
  const float* b_f   = (const float*)d_in[4];
  const float* Wih_b = (const float*)d_in[5];
  const float* Whh_b = (const float*)d_in[6];
  const float* b_b   = (const float*)d_in[7];
  const float* W_out = (const float*)d_in[8];
  const float* b_out = (const float*)d_in[9];
  const float* trans = (const float*)d_in[10];
  const float* h0    = (const float*)d_in[11];
  const float* c0    = (const float*)d_in[12];

  float* W = (float*)d_ws;
  float* zxF = W;                                    // 16 MB (dead after lstm)
  float* zxB = zxF + (size_t)T_LEN * G4;             // 16 MB
  float* feats = zxB + (size_t)T_LEN * G4;           // 512 KB
  uint32_t* hhF = (uint32_t*)(feats + (size_t)T_LEN * KTAGS);  // 1 MB (int8 h)
  uint32_t* hhB = hhF + (size_t)T_LEN * 64;          // 1 MB
  int* bestIdx = (int*)(hhB + (size_t)T_LEN * 64);
  unsigned char* bptr = (unsigned char*)(bestIdx + 16);  // 128 KB
  unsigned char* fmap = bptr + (size_t)T_LEN * KTAGS;    // 4 KB
  float* Cmat = zxF;                                 // overlay, 512 KB
  float* fvs = zxF + NCHUNK * 1024;                  // 129*32 floats

  float* out = (float*)d_out;  // out[0]=path_score, out[1..4096]=path tags

  zx_gemm<<<dim3(T_LEN / 8, 2), 256, 0, stream>>>(sent, embed, Wih_f, b_f, Wih_b, b_b, zxF, zxB);
  lstm_kernel<<<2, 512, 0, stream>>>(Whh_f, Whh_b, h0, c0, zxF, zxB, hhF, hhB);
  feat_kernel<<<T_LEN / 8, 256, 0, stream>>>(hhF, hhB, W_out, b_out, feats);
  vit_phaseA<<<NCHUNK, 1024, 0, stream>>>(feats, trans, Cmat);
  vit_phaseB<<<1, 64, 0, stream>>>(Cmat, trans, fvs, out, bestIdx);
  vit_phaseC<<<NCHUNK, 64, 0, stream>>>(feats, trans, fvs, bptr, fmap);
  vit_backtrace<<<1, 256, 0, stream>>>(bptr, fmap, bestIdx, out + 1);
}